// Round 18
// baseline (72.503 us; speedup 1.0000x reference)
//
#include <hip/hip_runtime.h>

#define NROI 1000
#define NCLS 81
#define NB   8
#define NLANE (NB*NCLS)        // 648 = 8 XCDs * 81
#define MAXM 1024
#define MAXKEEP 200
#define SCORE_T 0.5f
#define NT 512
#define NW 8                   // waves per block
#define SCAP 1024

typedef unsigned long long u64;
typedef unsigned int u32;

// --- exact-order helpers (no FMA contraction; must match f32 numpy reference) ---

__device__ __forceinline__ void decode_box(const float* __restrict__ roi,
                                           const float* __restrict__ dl,
                                           float& oy1, float& ox1,
                                           float& oy2, float& ox2) {
#pragma clang fp contract(off)
  float y1 = roi[0], x1 = roi[1], y2 = roi[2], x2 = roi[3];
  float h = y2 - y1;
  float w = x2 - x1;
  float cy = y1 + 0.5f * h;
  float cx = x1 + 0.5f * w;
  float d0 = dl[0] * 0.1f;
  float d1 = dl[1] * 0.1f;
  float d2 = dl[2] * 0.2f;
  float d3 = dl[3] * 0.2f;
  float ncy = d0 * h + cy;
  float ncx = d1 * w + cx;
  float nh = expf(d2) * h;
  float nw = expf(d3) * w;
  oy1 = ncy - 0.5f * nh;
  ox1 = ncx - 0.5f * nw;
  oy2 = ncy + 0.5f * nh;
  ox2 = ncx + 0.5f * nw;
}

__device__ __forceinline__ float area_f(float4 bx) {
#pragma clang fp contract(off)
  return (bx.z - bx.x) * (bx.w - bx.y);
}

// EXACT equivalent of: fl32(inter/den) > 0.5 (RNE), den>0 — proof in R6/R7:
// collapses to (inter+inter) > den in plain f32.
__device__ __forceinline__ bool hit_f(float4 bi, float ia, float4 bj, float ja) {
#pragma clang fp contract(off)
  float yy1 = fmaxf(bi.x, bj.x);
  float xx1 = fmaxf(bi.y, bj.y);
  float yy2 = fminf(bi.z, bj.z);
  float xx2 = fminf(bi.w, bj.w);
  float ih = fmaxf(yy2 - yy1, 0.0f);
  float iw = fmaxf(xx2 - xx1, 0.0f);
  float inter = ih * iw;
  float den = ia + ja;
  den = den - inter;
  den = den + 1e-8f;
  return (inter + inter) > den;
}

// key packing: [63:32] score bits, [31:15] (131071-flat) so lower flat wins,
//              [14:5] n (payload only), [4:0] zero. Empty slot = 0.
__device__ __forceinline__ u64 pack_key(u32 sbits, int flat, int n) {
  return ((u64)sbits << 32) | ((u64)(131071 - flat) << 15) | ((u64)n << 5);
}

// --- kernel 1: background rows (argmax==0), wave per row; zero bhist ---
__global__ __launch_bounds__(256) void bg_kernel(const float* __restrict__ probs,
                                                 int* __restrict__ bg,
                                                 int* __restrict__ bhist) {
  if (blockIdx.x < 8) {      // zero 8*256 ints across 8 blocks
    bhist[blockIdx.x * 256 + threadIdx.x] = 0;
  }
  int row = blockIdx.x * 4 + (threadIdx.x >> 6);
  int lane = threadIdx.x & 63;
  if (row >= NB * NROI) return;
  const float* p = probs + (size_t)row * NCLS;
  float m = -1e30f;
  for (int idx = 1 + lane; idx < NCLS; idx += 64) m = fmaxf(m, p[idx]);
  for (int off = 32; off; off >>= 1) m = fmaxf(m, __shfl_xor(m, off));
  if (lane == 0) bg[row] = (p[0] >= m) ? 1 : 0;  // argmax==0 iff p0 >= all others
}

// --- kernel 2 (fused): gather + counting sort + pipelined NMS (fixpoint resolve) ---
__global__ __launch_bounds__(NT) void gather_nms_kernel(
    const float* __restrict__ roi, const float* __restrict__ deltas,
    const float* __restrict__ probs, const int* __restrict__ bg,
    int* __restrict__ keep_count, u64* __restrict__ lane_key,
    int* __restrict__ bhist) {
  // XCD swizzle: 648 = 8*81; dispatch idx%8 = XCD -> XCD x owns batch x entirely
  int lane = (blockIdx.x % 8) * NCLS + blockIdx.x / 8;
  int b = lane / NCLS, c = lane % NCLS;
  int tid = threadIdx.x;
  int w = tid >> 6, l = tid & 63;

  // smem: [0,16K) sbox; aliases skeyU [0,8K) + skeyB [8K,16K) (dead pre-decode)
  //       [16K,24K) skey (final sorted); [24K,25K) bcnt; [25K,26K) bstart
  __shared__ alignas(16) char smem[26624];
  float4* sbox   = (float4*)smem;
  u64*    skeyU  = (u64*)smem;
  u64*    skeyB  = (u64*)(smem + 8192);
  u64*    skey   = (u64*)(smem + 16384);
  int*    bcnt   = (int*)(smem + 24576);
  int*    bstart = (int*)(smem + 25600);
  __shared__ u64 hmask8[NW][64];   // per-wave row-mask slots (no atomics)
  __shared__ u64 suppm8[NW];       // per-wave suppress ballots
  __shared__ u64 keepmask[16];
  __shared__ int scount, segbase[16];

  if (tid == 0) scount = 0;
  if (tid < 256) bcnt[tid] = 0;
  __syncthreads();

  // --- gather: score > 0.5 && !bg, + 8-bit score histogram (fused) ---
  for (int base_n = 0; base_n < NROI; base_n += NT) {
    int n = base_n + tid;
    bool cand = false;
    float s = 0.0f;
    if (n < NROI) {
      int row = b * NROI + n;
      s = probs[(size_t)row * NCLS + c];
      cand = (s > SCORE_T) && (bg[row] == 0);
    }
    u64 bal = __ballot(cand);
    int wb = 0;
    if (l == 0) wb = atomicAdd(&scount, (int)__popcll(bal));
    wb = __shfl(wb, 0);
    if (cand) {
      int off = (int)__popcll(bal & ((1ull << l) - 1ull));
      u32 sb = __float_as_uint(s);
      skeyU[wb + off] = ((u64)sb << 32) | (u64)(0xFFFFFFFFu - (u32)n);
      // scores in (0.5,1): exponent fixed -> top-8 mantissa bits are monotone
      atomicAdd(&bcnt[(sb >> 15) & 255], 1);
    }
  }
  __syncthreads();
  int M = scount;          // <= 1000
  int nchunks = (M + 63) >> 6;

  // --- descending bucket scan (wave 0): bstart/bcnt = start cursors ---
  if (w == 0) {
    int d0 = 4 * l, d1 = d0 + 1, d2 = d0 + 2, d3 = d0 + 3;
    int c0 = bcnt[255 - d0], c1 = bcnt[255 - d1];
    int c2 = bcnt[255 - d2], c3 = bcnt[255 - d3];
    int t = c0 + c1 + c2 + c3;
    int inc = t;
    for (int off = 1; off < 64; off <<= 1) {
      int v = __shfl_up(inc, off);
      if (l >= off) inc += v;
    }
    int excl = inc - t;
    int s0 = excl, s1 = excl + c0, s2 = excl + c0 + c1, s3 = excl + c0 + c1 + c2;
    bcnt[255 - d0] = s0; bstart[255 - d0] = s0;
    bcnt[255 - d1] = s1; bstart[255 - d1] = s1;
    bcnt[255 - d2] = s2; bstart[255 - d2] = s2;
    bcnt[255 - d3] = s3; bstart[255 - d3] = s3;
  }
  __syncthreads();

  // --- scatter into bucket runs (arrival order within run) ---
  for (int p = tid; p < M; p += NT) {
    u64 k = skeyU[p];
    int bkt = (int)((k >> 47) & 255);
    int pos = atomicAdd(&bcnt[bkt], 1);
    skeyB[pos] = k;
  }
  __syncthreads();

  // --- exact cleanup: global rank = bucket start + #greater in run ---
  for (int p = tid; p < M; p += NT) {
    u64 k = skeyB[p];
    int bkt = (int)((k >> 47) & 255);
    int st = bstart[bkt], en = bcnt[bkt];
    int r = st;
    for (int q = st; q < en; ++q) r += (skeyB[q] > k) ? 1 : 0;  // keys unique
    skey[r] = k;
  }
  if (tid < 16) {            // keep bitmask init: bits p < M set
    int rem = M - (tid << 6);
    keepmask[tid] = (rem >= 64) ? ~0ull : ((rem <= 0) ? 0ull : ((1ull << rem) - 1ull));
  }
  __syncthreads();   // skey sorted; skeyU/skeyB dead -> sbox region free

  // --- prologue: wave 7 decodes chunk 0 into sbox ---
  if (w == 7 && nchunks > 0) {
    u64 k = skey[l];
    int nn = (int)(0xFFFFFFFFu - (u32)(k & 0xFFFFFFFFull));
    int row = b * NROI + ((l < M) ? nn : 0);   // clamp: no OOB global reads
    float by1, bx1, by2, bx2;
    decode_box(roi + (size_t)row * 4, deltas + ((size_t)row * NCLS + c) * 4,
               by1, bx1, by2, bx2);
    sbox[l] = make_float4(by1, bx1, by2, bx2);
  }
  __syncthreads();

  // --- chunked greedy NMS: pipelined decode + fixpoint resolve (2 barriers) ---
  int kc = 0;
  const u64 stridemask = 0x0101010101010101ull << w;  // bits i: i%8 == w
  const u64 low = (1ull << l) - 1ull;
  for (int ck = 0; ck < nchunks; ++ck) {
    int start = ck << 6;
    float4 bj = sbox[start + l];       // own column box (coalesced)
    float ja = area_f(bj);

    // map: wave w computes rows i = 8w..8w+7 vs own column l
    {
      u64 part = 0;
#pragma unroll
      for (int r = 0; r < 8; ++r) {
        int i = (w << 3) + r;
        float4 bi = sbox[start + i];   // broadcast
        float ia = area_f(bi);
        if (hit_f(bi, ia, bj, ja)) part |= (1ull << i);
      }
      hmask8[w][l] = part;             // per-wave slot, no atomics
    }

    // suppress: own box vs kept boxes of ALL prev chunks, bits strided by wave
    {
      bool supp = false;
      for (int q = 0; q < ck; ++q) {
        u64 mq = keepmask[q] & stridemask;
        while (mq) {                   // wave-uniform
          int i = __ffsll((unsigned long long)mq) - 1;
          mq &= mq - 1;
          float4 bi = sbox[(q << 6) + i];   // broadcast
          float ia = area_f(bi);
          supp |= hit_f(bi, ia, bj, ja);
        }
      }
      u64 sb = __ballot(supp);
      if (l == 0) suppm8[w] = sb;      // unconditional (may be 0)
    }

    // wave 7: prefetch-decode chunk ck+1 (latency hidden under suppress/resolve)
    if (w == 7 && ck + 1 < nchunks) {
      int p = ((ck + 1) << 6) + l;
      u64 k = skey[p];
      int nn = (int)(0xFFFFFFFFu - (u32)(k & 0xFFFFFFFFull));
      int row = b * NROI + ((p < M) ? nn : 0);
      float by1, bx1, by2, bx2;
      decode_box(roi + (size_t)row * 4, deltas + ((size_t)row * NCLS + c) * 4,
                 by1, bx1, by2, bx2);
      sbox[p] = make_float4(by1, bx1, by2, bx2);
    }
    __syncthreads();   // B: hmask8, suppm8, next sbox tile all visible

    // resolve: ALL waves redundantly — parallel greedy fixpoint (proven exact).
    u64 rowm = hmask8[0][l] | hmask8[1][l] | hmask8[2][l] | hmask8[3][l]
             | hmask8[4][l] | hmask8[5][l] | hmask8[6][l] | hmask8[7][l];
    u64 sall = suppm8[0] | suppm8[1] | suppm8[2] | suppm8[3]
             | suppm8[4] | suppm8[5] | suppm8[6] | suppm8[7];
    int rem0 = M - start;
    u64 alive = (rem0 >= 64) ? ~0ull : ((rem0 <= 0) ? 0ull : ((1ull << rem0) - 1ull));
    u64 und = alive & ~sall;
    u64 kept = 0;
    while (und) {                      // wave-uniform; ~2-4 rounds typical
      bool isu = (und >> l) & 1;
      bool su = isu && ((rowm & kept & low) != 0ull);
      bool ke = isu && ((rowm & (kept | und) & low) == 0ull);
      u64 sm = __ballot(su);
      u64 km2 = __ballot(ke);
      kept |= km2;
      und &= ~(sm | km2);
    }
    if (tid == 0) keepmask[ck] = kept;
    kc += (int)__popcll(kept);         // identical across all waves
    if (kc >= MAXKEEP) break;          // block-uniform early termination
    __syncthreads();   // A: keepmask[ck] visible; resolve reads done pre-rewrite
  }
  __syncthreads();

  // --- parallel compaction + fused per-batch 8-bit histogram ---
  if (tid < 16) {
    int acc = 0;
    for (int i = 0; i < tid; ++i) acc += (int)__popcll(keepmask[i]);
    segbase[tid] = acc;
  }
  __syncthreads();
  int total = segbase[15] + (int)__popcll(keepmask[15]);
  for (int s = 0; s < 2; ++s) {
    int seg = (w << 1) + s;
    u64 word = keepmask[seg];
    int p = (seg << 6) + l;
    if ((word >> l) & 1) {
      int rank = segbase[seg] + (int)__popcll(word & ((1ull << l) - 1ull));
      if (rank < MAXKEEP) {
        u64 k = skey[p];
        u32 sbits = (u32)(k >> 32);
        int n = (int)(0xFFFFFFFFu - (u32)(k & 0xFFFFFFFFull));
        lane_key[(size_t)lane * MAXKEEP + rank] = pack_key(sbits, c * NROI + p, n);
        atomicAdd(&bhist[b * 256 + (int)((sbits >> 15) & 255)], 1);
      }
    }
  }
  if (tid == 0) keep_count[lane] = min(total, MAXKEEP);
}

// --- kernel 3: per-batch rank-direct top-200 (256-bucket histogram; no sort) ---
__global__ __launch_bounds__(512) void merge_kernel(
    const float* __restrict__ roi, const float* __restrict__ deltas,
    const int* __restrict__ keep_count, const u64* __restrict__ lane_key,
    const int* __restrict__ bhist,
    float* __restrict__ out_b, float* __restrict__ out_c, float* __restrict__ out_s) {
  int b = blockIdx.x;    // 8 blocks; idx%8 = XCD that produced batch b's keys
  int tid = threadIdx.x;
  int w = tid >> 6, l = tid & 63;

  __shared__ int mhist[256];
  __shared__ int mhsuf[256];
  __shared__ int mhcur[256];
  __shared__ int mcnts[NCLS];
  __shared__ int mtot, mscnt;
  __shared__ u64 msurv[SCAP];

  if (tid < 256) mhist[tid] = bhist[b * 256 + tid];
  for (int i = tid; i < NCLS; i += 512) mcnts[i] = keep_count[b * NCLS + i];
  if (tid == 0) mscnt = 0;
  for (int t = tid; t < MAXKEEP; t += 512) {   // zero-init all output slots
    size_t ob = ((size_t)b * MAXKEEP + t) * 4;
    out_b[ob + 0] = 0.0f; out_b[ob + 1] = 0.0f;
    out_b[ob + 2] = 0.0f; out_b[ob + 3] = 0.0f;
    out_c[b * MAXKEEP + t] = 0.0f;
    out_s[b * MAXKEEP + t] = 0.0f;
  }
  __syncthreads();

  // wave 0: suffix-EXCLUSIVE scan (higher bucket = higher score), 4/lane
  if (w == 0) {
    int g0 = 4 * l;
    int c0 = mhist[g0], c1 = mhist[g0 + 1], c2 = mhist[g0 + 2], c3 = mhist[g0 + 3];
    int t = c0 + c1 + c2 + c3;
    int acc = t;
    for (int off = 1; off < 64; off <<= 1) {
      int v = __shfl_down(acc, off);
      if (l + off < 64) acc += v;
    }
    if (l == 0) mtot = acc;            // total kept keys in batch
    int above = acc - t;               // keys in higher lane groups
    int s3 = above, s2 = above + c3, s1 = above + c3 + c2, s0 = above + c3 + c2 + c1;
    mhsuf[g0 + 3] = s3; mhcur[g0 + 3] = s3;
    mhsuf[g0 + 2] = s2; mhcur[g0 + 2] = s2;
    mhsuf[g0 + 1] = s1; mhcur[g0 + 1] = s1;
    mhsuf[g0 + 0] = s0; mhcur[g0 + 0] = s0;
  }
  __syncthreads();
  int valid = (mtot < MAXKEEP) ? mtot : MAXKEEP;

  // scatter survivors into rank-space slots (buckets whose base < 200)
  for (int s = tid; s < NCLS * MAXKEEP; s += 512) {
    int c2 = s / MAXKEEP, h = s % MAXKEEP;
    if (h < mcnts[c2]) {
      u64 k = lane_key[((size_t)(b * NCLS + c2)) * MAXKEEP + h];
      int bkt = (int)((k >> 47) & 255);
      if (mhsuf[bkt] < MAXKEEP) {
        int pos = atomicAdd(&mhcur[bkt], 1);
        if (pos < SCAP) { msurv[pos] = k; atomicAdd(&mscnt, 1); }
      }
    }
  }
  __syncthreads();
  int scnt = min(mscnt, SCAP);

  // rank-fix within bucket runs (~8 keys) + decode + direct write
  for (int p = tid; p < scnt; p += 512) {
    u64 k = msurv[p];
    int bkt = (int)((k >> 47) & 255);
    int st = mhsuf[bkt];
    int en = st + mhist[bkt];
    if (en > SCAP) en = SCAP;
    int r = st;
    for (int q = st; q < en; ++q) r += (msurv[q] > k) ? 1 : 0;  // keys unique
    if (r < valid) {
      int flat = 131071 - (int)((k >> 15) & 0x1FFFF);
      int c2 = flat / NROI;
      int n = (int)((k >> 5) & 0x3FF);
      int row = b * NROI + n;
      float by1, bx1, by2, bx2;
      decode_box(roi + (size_t)row * 4, deltas + ((size_t)row * NCLS + c2) * 4,
                 by1, bx1, by2, bx2);
      size_t ob = ((size_t)b * MAXKEEP + r) * 4;
      out_b[ob + 0] = fminf(fmaxf(by1, 0.0f), 1.0f);
      out_b[ob + 1] = fminf(fmaxf(bx1, 0.0f), 1.0f);
      out_b[ob + 2] = fminf(fmaxf(by2, 0.0f), 1.0f);
      out_b[ob + 3] = fminf(fmaxf(bx2, 0.0f), 1.0f);
      out_c[b * MAXKEEP + r] = (float)c2;
      out_s[b * MAXKEEP + r] = __uint_as_float((u32)(k >> 32));
    }
  }
}

extern "C" void kernel_launch(void* const* d_in, const int* in_sizes, int n_in,
                              void* d_out, int out_size, void* d_ws, size_t ws_size,
                              hipStream_t stream) {
  const float* roi    = (const float*)d_in[0];  // [8,1000,4]
  const float* deltas = (const float*)d_in[1];  // [8,1000,324]
  const float* probs  = (const float*)d_in[2];  // [8,1000,81]

  char* ws = (char*)d_ws;
  int* bg         = (int*)(ws);                 // 32000 B
  int* bhist      = (int*)(ws + 32768);         // 8*256*4 = 8192 B
  int* keep_count = (int*)(ws + 40960);         // 2592 B
  u64* lane_key   = (u64*)(ws + 45056);         // 648*200*8 = 1,036,800 B

  float* out_b = (float*)d_out;                 // [8,200,4]
  float* out_c = out_b + NB * MAXKEEP * 4;      // [8,200]
  float* out_s = out_c + NB * MAXKEEP;          // [8,200]

  bg_kernel<<<(NB * NROI + 3) / 4, 256, 0, stream>>>(probs, bg, bhist);
  gather_nms_kernel<<<NLANE, NT, 0, stream>>>(roi, deltas, probs, bg,
                                              keep_count, lane_key, bhist);
  merge_kernel<<<NB, 512, 0, stream>>>(roi, deltas, keep_count, lane_key, bhist,
                                       out_b, out_c, out_s);
}

// Round 19
// 61.048 us; speedup vs baseline: 1.1876x; 1.1876x over previous
//
#include <hip/hip_runtime.h>

#define NROI 1000
#define NCLS 81
#define NB   8
#define NLANE (NB*NCLS)        // 648 = 8 XCDs * 81
#define MAXM 1024
#define MAXKEEP 200
#define SCORE_T 0.5f
#define NT 512
#define NW 8                   // waves per block
#define SCAP 1024

typedef unsigned long long u64;
typedef unsigned int u32;

// --- exact-order helpers (no FMA contraction; must match f32 numpy reference) ---

__device__ __forceinline__ void decode_box(const float* __restrict__ roi,
                                           const float* __restrict__ dl,
                                           float& oy1, float& ox1,
                                           float& oy2, float& ox2) {
#pragma clang fp contract(off)
  float y1 = roi[0], x1 = roi[1], y2 = roi[2], x2 = roi[3];
  float h = y2 - y1;
  float w = x2 - x1;
  float cy = y1 + 0.5f * h;
  float cx = x1 + 0.5f * w;
  float d0 = dl[0] * 0.1f;
  float d1 = dl[1] * 0.1f;
  float d2 = dl[2] * 0.2f;
  float d3 = dl[3] * 0.2f;
  float ncy = d0 * h + cy;
  float ncx = d1 * w + cx;
  float nh = expf(d2) * h;
  float nw = expf(d3) * w;
  oy1 = ncy - 0.5f * nh;
  ox1 = ncx - 0.5f * nw;
  oy2 = ncy + 0.5f * nh;
  ox2 = ncx + 0.5f * nw;
}

__device__ __forceinline__ float area_f(float4 bx) {
#pragma clang fp contract(off)
  return (bx.z - bx.x) * (bx.w - bx.y);
}

// EXACT equivalent of: fl32(inter/den) > 0.5 (RNE), den>0 — proof in R6/R7:
// collapses to (inter+inter) > den in plain f32.
__device__ __forceinline__ bool hit_f(float4 bi, float ia, float4 bj, float ja) {
#pragma clang fp contract(off)
  float yy1 = fmaxf(bi.x, bj.x);
  float xx1 = fmaxf(bi.y, bj.y);
  float yy2 = fminf(bi.z, bj.z);
  float xx2 = fminf(bi.w, bj.w);
  float ih = fmaxf(yy2 - yy1, 0.0f);
  float iw = fmaxf(xx2 - xx1, 0.0f);
  float inter = ih * iw;
  float den = ia + ja;
  den = den - inter;
  den = den + 1e-8f;
  return (inter + inter) > den;
}

// key packing: [63:32] score bits, [31:15] (131071-flat) so lower flat wins,
//              [14:5] n (payload only), [4:0] zero. Empty slot = 0.
__device__ __forceinline__ u64 pack_key(u32 sbits, int flat, int n) {
  return ((u64)sbits << 32) | ((u64)(131071 - flat) << 15) | ((u64)n << 5);
}

// --- kernel 1: background rows (argmax==0), wave per row; zero bhist ---
__global__ __launch_bounds__(256) void bg_kernel(const float* __restrict__ probs,
                                                 int* __restrict__ bg,
                                                 int* __restrict__ bhist) {
  if (blockIdx.x < 8) {      // zero 8*256 ints across 8 blocks
    bhist[blockIdx.x * 256 + threadIdx.x] = 0;
  }
  int row = blockIdx.x * 4 + (threadIdx.x >> 6);
  int lane = threadIdx.x & 63;
  if (row >= NB * NROI) return;
  const float* p = probs + (size_t)row * NCLS;
  float m = -1e30f;
  for (int idx = 1 + lane; idx < NCLS; idx += 64) m = fmaxf(m, p[idx]);
  for (int off = 32; off; off >>= 1) m = fmaxf(m, __shfl_xor(m, off));
  if (lane == 0) bg[row] = (p[0] >= m) ? 1 : 0;  // argmax==0 iff p0 >= all others
}

// --- kernel 2 (fused): gather + counting sort + pipelined NMS (fixpoint resolve) ---
__global__ __launch_bounds__(NT) void gather_nms_kernel(
    const float* __restrict__ roi, const float* __restrict__ deltas,
    const float* __restrict__ probs, const int* __restrict__ bg,
    int* __restrict__ keep_count, u64* __restrict__ lane_key,
    int* __restrict__ bhist) {
  // XCD swizzle: 648 = 8*81; dispatch idx%8 = XCD -> XCD x owns batch x entirely
  int lane = (blockIdx.x % 8) * NCLS + blockIdx.x / 8;
  int b = lane / NCLS, c = lane % NCLS;
  int tid = threadIdx.x;
  int w = tid >> 6, l = tid & 63;

  // smem: [0,16K) sbox; aliases skeyU [0,8K) + skeyB [8K,16K) (dead pre-decode)
  //       [16K,24K) skey (final sorted); [24K,25K) bcnt; [25K,26K) bstart
  __shared__ alignas(16) char smem[26624];
  float4* sbox   = (float4*)smem;
  u64*    skeyU  = (u64*)smem;
  u64*    skeyB  = (u64*)(smem + 8192);
  u64*    skey   = (u64*)(smem + 16384);
  int*    bcnt   = (int*)(smem + 24576);
  int*    bstart = (int*)(smem + 25600);
  __shared__ float4 klist[320];    // dense kept-box list (max 199+64 appends)
  __shared__ u64 hmask8[NW][64];   // per-wave row-mask slots (no atomics)
  __shared__ u64 suppm8[NW];       // per-wave suppress ballots
  __shared__ u64 keepmask[16];
  __shared__ int scount, segbase[16];

  if (tid == 0) scount = 0;
  if (tid < 256) bcnt[tid] = 0;
  __syncthreads();

  // --- gather: score > 0.5 && !bg, + 8-bit score histogram (fused) ---
  for (int base_n = 0; base_n < NROI; base_n += NT) {
    int n = base_n + tid;
    bool cand = false;
    float s = 0.0f;
    if (n < NROI) {
      int row = b * NROI + n;
      s = probs[(size_t)row * NCLS + c];
      cand = (s > SCORE_T) && (bg[row] == 0);
    }
    u64 bal = __ballot(cand);
    int wb = 0;
    if (l == 0) wb = atomicAdd(&scount, (int)__popcll(bal));
    wb = __shfl(wb, 0);
    if (cand) {
      int off = (int)__popcll(bal & ((1ull << l) - 1ull));
      u32 sb = __float_as_uint(s);
      skeyU[wb + off] = ((u64)sb << 32) | (u64)(0xFFFFFFFFu - (u32)n);
      // scores in (0.5,1): exponent fixed -> top-8 mantissa bits are monotone
      atomicAdd(&bcnt[(sb >> 15) & 255], 1);
    }
  }
  __syncthreads();
  int M = scount;          // <= 1000
  int nchunks = (M + 63) >> 6;

  // --- descending bucket scan (wave 0): bstart/bcnt = start cursors ---
  if (w == 0) {
    int d0 = 4 * l, d1 = d0 + 1, d2 = d0 + 2, d3 = d0 + 3;
    int c0 = bcnt[255 - d0], c1 = bcnt[255 - d1];
    int c2 = bcnt[255 - d2], c3 = bcnt[255 - d3];
    int t = c0 + c1 + c2 + c3;
    int inc = t;
    for (int off = 1; off < 64; off <<= 1) {
      int v = __shfl_up(inc, off);
      if (l >= off) inc += v;
    }
    int excl = inc - t;
    int s0 = excl, s1 = excl + c0, s2 = excl + c0 + c1, s3 = excl + c0 + c1 + c2;
    bcnt[255 - d0] = s0; bstart[255 - d0] = s0;
    bcnt[255 - d1] = s1; bstart[255 - d1] = s1;
    bcnt[255 - d2] = s2; bstart[255 - d2] = s2;
    bcnt[255 - d3] = s3; bstart[255 - d3] = s3;
  }
  __syncthreads();

  // --- scatter into bucket runs (arrival order within run) ---
  for (int p = tid; p < M; p += NT) {
    u64 k = skeyU[p];
    int bkt = (int)((k >> 47) & 255);
    int pos = atomicAdd(&bcnt[bkt], 1);
    skeyB[pos] = k;
  }
  __syncthreads();

  // --- exact cleanup: global rank = bucket start + #greater in run ---
  for (int p = tid; p < M; p += NT) {
    u64 k = skeyB[p];
    int bkt = (int)((k >> 47) & 255);
    int st = bstart[bkt], en = bcnt[bkt];
    int r = st;
    for (int q = st; q < en; ++q) r += (skeyB[q] > k) ? 1 : 0;  // keys unique
    skey[r] = k;
  }
  if (tid < 16) {            // keep bitmask init: bits p < M set
    int rem = M - (tid << 6);
    keepmask[tid] = (rem >= 64) ? ~0ull : ((rem <= 0) ? 0ull : ((1ull << rem) - 1ull));
  }
  __syncthreads();   // skey sorted; skeyU/skeyB dead -> sbox region free

  // --- prologue: wave 7 decodes chunk 0 into sbox ---
  if (w == 7 && nchunks > 0) {
    u64 k = skey[l];
    int nn = (int)(0xFFFFFFFFu - (u32)(k & 0xFFFFFFFFull));
    int row = b * NROI + ((l < M) ? nn : 0);   // clamp: no OOB global reads
    float by1, bx1, by2, bx2;
    decode_box(roi + (size_t)row * 4, deltas + ((size_t)row * NCLS + c) * 4,
               by1, bx1, by2, bx2);
    sbox[l] = make_float4(by1, bx1, by2, bx2);
  }
  __syncthreads();

  // --- chunked greedy NMS: pipelined decode + fixpoint resolve (2 barriers) ---
  int kc = 0;   // kept so far (block-uniform; klist[0..kc) = kept boxes, dense)
  const u64 low = (1ull << l) - 1ull;
  for (int ck = 0; ck < nchunks; ++ck) {
    int start = ck << 6;
    float4 bj = sbox[start + l];       // own column box (coalesced)
    float ja = area_f(bj);

    // map: wave w computes rows i = 8w..8w+7 vs own column l
    {
      u64 part = 0;
#pragma unroll
      for (int r = 0; r < 8; ++r) {
        int i = (w << 3) + r;
        float4 bi = sbox[start + i];   // broadcast
        float ia = area_f(bi);
        if (hit_f(bi, ia, bj, ja)) part |= (1ull << i);
      }
      hmask8[w][l] = part;             // per-wave slot, no atomics
    }

    // suppress: own box vs dense kept list (countable loop -> pipelined loads)
    {
      bool supp = false;
      for (int i = w; i < kc; i += NW) {
        float4 bi = klist[i];          // broadcast, address independent of data
        float ia = area_f(bi);
        supp |= hit_f(bi, ia, bj, ja);
      }
      u64 sb = __ballot(supp);
      if (l == 0) suppm8[w] = sb;      // unconditional (may be 0)
    }

    // wave 7: prefetch-decode chunk ck+1 (latency hidden under suppress/resolve)
    if (w == 7 && ck + 1 < nchunks) {
      int p = ((ck + 1) << 6) + l;
      u64 k = skey[p];
      int nn = (int)(0xFFFFFFFFu - (u32)(k & 0xFFFFFFFFull));
      int row = b * NROI + ((p < M) ? nn : 0);
      float by1, bx1, by2, bx2;
      decode_box(roi + (size_t)row * 4, deltas + ((size_t)row * NCLS + c) * 4,
                 by1, bx1, by2, bx2);
      sbox[p] = make_float4(by1, bx1, by2, bx2);
    }
    __syncthreads();   // B: hmask8, suppm8, next sbox tile all visible

    // resolve: ALL waves redundantly — parallel greedy fixpoint (proven exact).
    u64 rowm = hmask8[0][l] | hmask8[1][l] | hmask8[2][l] | hmask8[3][l]
             | hmask8[4][l] | hmask8[5][l] | hmask8[6][l] | hmask8[7][l];
    u64 sall = suppm8[0] | suppm8[1] | suppm8[2] | suppm8[3]
             | suppm8[4] | suppm8[5] | suppm8[6] | suppm8[7];
    int rem0 = M - start;
    u64 alive = (rem0 >= 64) ? ~0ull : ((rem0 <= 0) ? 0ull : ((1ull << rem0) - 1ull));
    u64 und = alive & ~sall;
    u64 kept = 0;
    while (und) {                      // wave-uniform; ~2-4 rounds typical
      bool isu = (und >> l) & 1;
      bool su = isu && ((rowm & kept & low) != 0ull);
      bool ke = isu && ((rowm & (kept | und) & low) == 0ull);
      u64 sm = __ballot(su);
      u64 km2 = __ballot(ke);
      kept |= km2;
      und &= ~(sm | km2);
    }
    // wave 0: append kept boxes (register-resident) to the dense list
    if (w == 0 && ((kept >> l) & 1)) {
      klist[kc + (int)__popcll(kept & low)] = bj;
    }
    if (tid == 0) keepmask[ck] = kept;
    kc += (int)__popcll(kept);         // identical across all waves
    if (kc >= MAXKEEP) break;          // block-uniform early termination
    __syncthreads();   // A: keepmask/klist visible; resolve reads done pre-rewrite
  }
  __syncthreads();

  // --- parallel compaction + LDS-aggregated per-batch 8-bit histogram ---
  if (tid < 16) {
    int acc = 0;
    for (int i = 0; i < tid; ++i) acc += (int)__popcll(keepmask[i]);
    segbase[tid] = acc;
  }
  if (tid < 256) bcnt[tid] = 0;        // reuse dead bcnt as local histogram
  __syncthreads();
  int total = segbase[15] + (int)__popcll(keepmask[15]);
  for (int s = 0; s < 2; ++s) {
    int seg = (w << 1) + s;
    u64 word = keepmask[seg];
    int p = (seg << 6) + l;
    if ((word >> l) & 1) {
      int rank = segbase[seg] + (int)__popcll(word & ((1ull << l) - 1ull));
      if (rank < MAXKEEP) {
        u64 k = skey[p];
        u32 sbits = (u32)(k >> 32);
        int n = (int)(0xFFFFFFFFu - (u32)(k & 0xFFFFFFFFull));
        lane_key[(size_t)lane * MAXKEEP + rank] = pack_key(sbits, c * NROI + p, n);
        atomicAdd(&bcnt[(int)((sbits >> 15) & 255)], 1);   // LDS, low contention
      }
    }
  }
  __syncthreads();
  if (tid < 256 && bcnt[tid] != 0)     // one aggregated global atomic per bucket
    atomicAdd(&bhist[b * 256 + tid], bcnt[tid]);
  if (tid == 0) keep_count[lane] = min(total, MAXKEEP);
}

// --- kernel 3: per-batch rank-direct top-200 (256-bucket histogram; no sort) ---
__global__ __launch_bounds__(512) void merge_kernel(
    const float* __restrict__ roi, const float* __restrict__ deltas,
    const int* __restrict__ keep_count, const u64* __restrict__ lane_key,
    const int* __restrict__ bhist,
    float* __restrict__ out_b, float* __restrict__ out_c, float* __restrict__ out_s) {
  int b = blockIdx.x;    // 8 blocks; idx%8 = XCD that produced batch b's keys
  int tid = threadIdx.x;
  int w = tid >> 6, l = tid & 63;

  __shared__ int mhist[256];
  __shared__ int mhsuf[256];
  __shared__ int mhcur[256];
  __shared__ int mcnts[NCLS];
  __shared__ int mtot, mscnt;
  __shared__ u64 msurv[SCAP];

  if (tid < 256) mhist[tid] = bhist[b * 256 + tid];
  for (int i = tid; i < NCLS; i += 512) mcnts[i] = keep_count[b * NCLS + i];
  if (tid == 0) mscnt = 0;
  for (int t = tid; t < MAXKEEP; t += 512) {   // zero-init all output slots
    size_t ob = ((size_t)b * MAXKEEP + t) * 4;
    out_b[ob + 0] = 0.0f; out_b[ob + 1] = 0.0f;
    out_b[ob + 2] = 0.0f; out_b[ob + 3] = 0.0f;
    out_c[b * MAXKEEP + t] = 0.0f;
    out_s[b * MAXKEEP + t] = 0.0f;
  }
  __syncthreads();

  // wave 0: suffix-EXCLUSIVE scan (higher bucket = higher score), 4/lane
  if (w == 0) {
    int g0 = 4 * l;
    int c0 = mhist[g0], c1 = mhist[g0 + 1], c2 = mhist[g0 + 2], c3 = mhist[g0 + 3];
    int t = c0 + c1 + c2 + c3;
    int acc = t;
    for (int off = 1; off < 64; off <<= 1) {
      int v = __shfl_down(acc, off);
      if (l + off < 64) acc += v;
    }
    if (l == 0) mtot = acc;            // total kept keys in batch
    int above = acc - t;               // keys in higher lane groups
    int s3 = above, s2 = above + c3, s1 = above + c3 + c2, s0 = above + c3 + c2 + c1;
    mhsuf[g0 + 3] = s3; mhcur[g0 + 3] = s3;
    mhsuf[g0 + 2] = s2; mhcur[g0 + 2] = s2;
    mhsuf[g0 + 1] = s1; mhcur[g0 + 1] = s1;
    mhsuf[g0 + 0] = s0; mhcur[g0 + 0] = s0;
  }
  __syncthreads();
  int valid = (mtot < MAXKEEP) ? mtot : MAXKEEP;

  // scatter survivors into rank-space slots (buckets whose base < 200)
  for (int s = tid; s < NCLS * MAXKEEP; s += 512) {
    int c2 = s / MAXKEEP, h = s % MAXKEEP;
    if (h < mcnts[c2]) {
      u64 k = lane_key[((size_t)(b * NCLS + c2)) * MAXKEEP + h];
      int bkt = (int)((k >> 47) & 255);
      if (mhsuf[bkt] < MAXKEEP) {
        int pos = atomicAdd(&mhcur[bkt], 1);
        if (pos < SCAP) { msurv[pos] = k; atomicAdd(&mscnt, 1); }
      }
    }
  }
  __syncthreads();
  int scnt = min(mscnt, SCAP);

  // rank-fix within bucket runs (~8 keys) + decode + direct write
  for (int p = tid; p < scnt; p += 512) {
    u64 k = msurv[p];
    int bkt = (int)((k >> 47) & 255);
    int st = mhsuf[bkt];
    int en = st + mhist[bkt];
    if (en > SCAP) en = SCAP;
    int r = st;
    for (int q = st; q < en; ++q) r += (msurv[q] > k) ? 1 : 0;  // keys unique
    if (r < valid) {
      int flat = 131071 - (int)((k >> 15) & 0x1FFFF);
      int c2 = flat / NROI;
      int n = (int)((k >> 5) & 0x3FF);
      int row = b * NROI + n;
      float by1, bx1, by2, bx2;
      decode_box(roi + (size_t)row * 4, deltas + ((size_t)row * NCLS + c2) * 4,
                 by1, bx1, by2, bx2);
      size_t ob = ((size_t)b * MAXKEEP + r) * 4;
      out_b[ob + 0] = fminf(fmaxf(by1, 0.0f), 1.0f);
      out_b[ob + 1] = fminf(fmaxf(bx1, 0.0f), 1.0f);
      out_b[ob + 2] = fminf(fmaxf(by2, 0.0f), 1.0f);
      out_b[ob + 3] = fminf(fmaxf(bx2, 0.0f), 1.0f);
      out_c[b * MAXKEEP + r] = (float)c2;
      out_s[b * MAXKEEP + r] = __uint_as_float((u32)(k >> 32));
    }
  }
}

extern "C" void kernel_launch(void* const* d_in, const int* in_sizes, int n_in,
                              void* d_out, int out_size, void* d_ws, size_t ws_size,
                              hipStream_t stream) {
  const float* roi    = (const float*)d_in[0];  // [8,1000,4]
  const float* deltas = (const float*)d_in[1];  // [8,1000,324]
  const float* probs  = (const float*)d_in[2];  // [8,1000,81]

  char* ws = (char*)d_ws;
  int* bg         = (int*)(ws);                 // 32000 B
  int* bhist      = (int*)(ws + 32768);         // 8*256*4 = 8192 B
  int* keep_count = (int*)(ws + 40960);         // 2592 B
  u64* lane_key   = (u64*)(ws + 45056);         // 648*200*8 = 1,036,800 B

  float* out_b = (float*)d_out;                 // [8,200,4]
  float* out_c = out_b + NB * MAXKEEP * 4;      // [8,200]
  float* out_s = out_c + NB * MAXKEEP;          // [8,200]

  bg_kernel<<<(NB * NROI + 3) / 4, 256, 0, stream>>>(probs, bg, bhist);
  gather_nms_kernel<<<NLANE, NT, 0, stream>>>(roi, deltas, probs, bg,
                                              keep_count, lane_key, bhist);
  merge_kernel<<<NB, 512, 0, stream>>>(roi, deltas, keep_count, lane_key, bhist,
                                       out_b, out_c, out_s);
}